// Round 3
// baseline (825.708 us; speedup 1.0000x reference)
//
#include <hip/hip_runtime.h>

#define NN 50000
#define EE 800000
#define DD 64
#define NL 3
#define UIN 832
#define DELTA_F 2.833213344056216f
#define SLOPE 0.01f
#define SCAN_BLKS 196  // 196*256 = 50176 >= NN
#define TUNIT 64       // work units per fused block
#define NBLK 15625     // ceil((EE + 4*NN)/TUNIT) = 1e6/64
#define NMAX 16        // max nodes per fused block (TUNIT/4)

typedef __attribute__((ext_vector_type(8))) short short8;
typedef __attribute__((ext_vector_type(4))) float floatx4;

// ---- static device buffers (fully rewritten every call) ----
__device__ __align__(16) float          g_hf[2][NN * DD];       // fp32 master h
__device__ __align__(16) unsigned short g_hb[2][NN * DD];       // bf16 copy for gathers
__device__ __align__(16) unsigned short g_x[NN * UIN];          // [h | agg | agg*s1 | agg*s2] bf16
__device__ __align__(16) unsigned short g_BfragU[NL * 26 * 4 * 512]; // W_comb^T fragments
__device__ __align__(16) unsigned short g_BfragM[NL * 4 * 4 * 512];  // M_w^T fragments
__device__ float g_bcomb[NL * DD];
__device__ int   g_cnt[NN];
__device__ int   g_roff[NN + 1];
__device__ int   g_uoff[NN + 1];
__device__ int   g_csrc[EE];      // src node per CSR row
__device__ int   g_cdst[EE];      // dst node per CSR row
__device__ int   g_nstart[NBLK + 1];
__device__ int   g_bsum[SCAN_BLKS], g_boff[SCAN_BLKS];
__device__ int   g_bsum2[SCAN_BLKS], g_boff2[SCAN_BLKS];

__device__ __forceinline__ float bf2f(unsigned short u) {
  return __uint_as_float(((unsigned)u) << 16);
}
__device__ __forceinline__ unsigned short f2bf(float f) {
  unsigned u = __float_as_uint(f);
  return (unsigned short)((u + 0x7FFFu + ((u >> 16) & 1u)) >> 16);
}
__device__ __forceinline__ float lrelu(float x) { return x >= 0.f ? x : SLOPE * x; }
// order-preserving f32 <-> u32 map (for atomicMax/Min on LDS ints)
__device__ __forceinline__ unsigned omap(float f) {
  unsigned u = __float_as_uint(f);
  return ((int)u < 0) ? ~u : (u | 0x80000000u);
}
__device__ __forceinline__ float oinv(unsigned i) {
  unsigned u = ((int)i < 0) ? (i ^ 0x80000000u) : ~i;
  return __uint_as_float(u);
}

// ---- prep: h = round(h*100)/100, plus bf16 copy ----
__global__ void __launch_bounds__(256) k_prep(const float* __restrict__ h) {
  int i = blockIdx.x * 256 + threadIdx.x;
  if (i >= NN * DD) return;
  float v = rintf(h[i] * 100.f) / 100.f;
  g_hf[0][i] = v;
  g_hb[0][i] = f2bf(v);
}

__global__ void __launch_bounds__(256) k_zero() {
  int i = blockIdx.x * 256 + threadIdx.x;
  if (i < NN) g_cnt[i] = 0;
}

__global__ void __launch_bounds__(256) k_hist(const int* __restrict__ dst) {
  int i = blockIdx.x * 256 + threadIdx.x;
  if (i < EE) atomicAdd(&g_cnt[dst[i]], 1);
}

// ---- dual hierarchical scan: degrees -> g_roff, units(max(deg,4)) -> g_uoff ----
__global__ void __launch_bounds__(256) k_scan_a() {
  __shared__ int sh[256], sh2[256];
  int t = threadIdx.x;
  int idx = blockIdx.x * 256 + t;
  int d = (idx < NN) ? g_cnt[idx] : 0;
  sh[t] = d;
  sh2[t] = (idx < NN) ? max(d, 4) : 0;
  __syncthreads();
  for (int off = 128; off > 0; off >>= 1) {
    if (t < off) { sh[t] += sh[t + off]; sh2[t] += sh2[t + off]; }
    __syncthreads();
  }
  if (t == 0) { g_bsum[blockIdx.x] = sh[0]; g_bsum2[blockIdx.x] = sh2[0]; }
}

__global__ void __launch_bounds__(256) k_scan_b() {
  __shared__ int sh[256], sh2[256];
  int t = threadIdx.x;
  sh[t] = (t < SCAN_BLKS) ? g_bsum[t] : 0;
  sh2[t] = (t < SCAN_BLKS) ? g_bsum2[t] : 0;
  __syncthreads();
  for (int off = 1; off < 256; off <<= 1) {
    int v = (t >= off) ? sh[t - off] : 0;
    int v2 = (t >= off) ? sh2[t - off] : 0;
    __syncthreads();
    sh[t] += v; sh2[t] += v2;
    __syncthreads();
  }
  if (t < SCAN_BLKS) {
    g_boff[t] = (t == 0) ? 0 : sh[t - 1];
    g_boff2[t] = (t == 0) ? 0 : sh2[t - 1];
  }
  if (t == 255) g_uoff[NN] = sh2[255];  // total units
}

__global__ void __launch_bounds__(256) k_scan_c() {
  __shared__ int sh[256], sh2[256];
  int t = threadIdx.x;
  int idx = blockIdx.x * 256 + t;
  int v = (idx < NN) ? g_cnt[idx] : 0;
  int v2 = (idx < NN) ? max(v, 4) : 0;
  sh[t] = v; sh2[t] = v2;
  __syncthreads();
  for (int off = 1; off < 256; off <<= 1) {
    int x = (t >= off) ? sh[t - off] : 0;
    int x2 = (t >= off) ? sh2[t - off] : 0;
    __syncthreads();
    sh[t] += x; sh2[t] += x2;
    __syncthreads();
  }
  if (idx < NN) {
    g_roff[idx] = g_boff[blockIdx.x] + sh[t] - v;     // exclusive prefix
    g_uoff[idx] = g_boff2[blockIdx.x] + sh2[t] - v2;
  }
  if (blockIdx.x == 0 && t == 0) g_roff[NN] = EE;
}

// ---- per-block node partition: nstart[b] = lower_bound(uoff, b*TUNIT) ----
__global__ void __launch_bounds__(256) k_part() {
  int b = blockIdx.x * 256 + threadIdx.x;
  if (b > NBLK) return;
  int target = b * TUNIT;
  int lo = 0, hi = NN;
  while (lo < hi) {
    int mid = (lo + hi) >> 1;
    if (g_uoff[mid] < target) lo = mid + 1; else hi = mid;
  }
  g_nstart[b] = lo;
}

__global__ void __launch_bounds__(256) k_scatter(const int* __restrict__ src,
                                                 const int* __restrict__ dst) {
  int i = blockIdx.x * 256 + threadIdx.x;
  if (i < EE) {
    int d = dst[i];
    int p = atomicAdd(&g_cnt[d], 1);
    int pos = g_roff[d] + p;
    g_csrc[pos] = src[i];
    g_cdst[pos] = d;
  }
}

// ---- W_comb = mix_w @ U_w, written directly into MFMA B-fragment layout ----
__global__ void __launch_bounds__(256) k_wcomb(const float* __restrict__ Uw,
                                               const float* __restrict__ mixw) {
  int idx = blockIdx.x * 256 + threadIdx.x;  // NL*DD*UIN = 159744
  if (idx >= NL * DD * UIN) return;
  int l = idx / (DD * UIN);
  int rem = idx - l * (DD * UIN);
  int d = rem / UIN;
  int k = rem - d * UIN;
  const float* xw = mixw + (l * DD + d) * DD;
  const float* uc = Uw + (size_t)l * DD * UIN + k;
  float s = 0.f;
  for (int j = 0; j < DD; ++j) s += xw[j] * uc[(size_t)j * UIN];
  int kt = k >> 5, kr = k & 31, g = kr >> 3, j8 = kr & 7, nb = d >> 4;
  int ln = (g << 4) | (d & 15);
  g_BfragU[(((l * 26 + kt) * 4 + nb) << 9) + ln * 8 + j8] = f2bf(s);
}

__global__ void __launch_bounds__(256) k_mfrag(const float* __restrict__ Mw) {
  int idx = blockIdx.x * 256 + threadIdx.x;  // NL*DD*128 = 24576
  if (idx >= NL * DD * 128) return;
  int l = idx >> 13;
  int rem = idx & 8191;
  int d = rem >> 7;
  int k = rem & 127;
  float w = Mw[idx];
  int kt = k >> 5, kr = k & 31, g = kr >> 3, j8 = kr & 7, nb = d >> 4;
  int ln = (g << 4) | (d & 15);
  g_BfragM[(((l * 4 + kt) * 4 + nb) << 9) + ln * 8 + j8] = f2bf(w);
}

__global__ void __launch_bounds__(192) k_bcomb(const float* __restrict__ mixw,
                                               const float* __restrict__ Ub,
                                               const float* __restrict__ mixb) {
  int idx = threadIdx.x;  // 192
  int l = idx >> 6, d = idx & 63;
  const float* xw = mixw + (l * DD + d) * DD;
  const float* ub = Ub + l * DD;
  float s = 0.f;
  for (int j = 0; j < DD; ++j) s += xw[j] * ub[j];
  g_bcomb[idx] = s + mixb[idx];
}

// ---- fused: edge GEMM (MFMA) -> LDS -> segmented aggregation -> x rows ----
__global__ void __launch_bounds__(256) k_msgagg(const float* __restrict__ Mb,
                                                int L, int par) {
  __shared__ unsigned short sm_msg[64 * 66];
  __shared__ float sm_s[NMAX * 64], sm_q[NMAX * 64];
  __shared__ unsigned sm_mx[NMAX * 64], sm_mn[NMAX * 64];
  __shared__ int sm_rownode[64];

  int b = blockIdx.x;
  int n0 = g_nstart[b], n1 = g_nstart[b + 1];
  if (n0 >= n1) return;
  int t = threadIdx.x;
  int lane = t & 63;
  int w = t >> 6;
  int r0 = g_roff[n0], rend = g_roff[n1];
  int nrows = rend - r0;

  // init accumulators
  for (int i = t; i < NMAX * 64; i += 256) {
    sm_s[i] = 0.f; sm_q[i] = 0.f; sm_mx[i] = 0u; sm_mn[i] = 0xFFFFFFFFu;
  }

  // per-lane M-weight fragments + bias
  short8 bf[16];
  const unsigned short* bp = g_BfragM + ((size_t)L * 16) * 512;
#pragma unroll
  for (int i = 0; i < 16; ++i) bf[i] = *(const short8*)(bp + i * 512 + lane * 8);
  float mb[4];
#pragma unroll
  for (int nb = 0; nb < 4; ++nb) mb[nb] = Mb[L * DD + nb * 16 + (lane & 15)];
  const unsigned short* hb = g_hb[par];
  int chunk = (lane >> 4) << 3;
  int c = t & 63, g = t >> 6;  // aggregation roles

  for (int cb = 0; cb < nrows; cb += 64) {
    int m = min(64, nrows - cb);
    if (t < 64) sm_rownode[t] = (t < m) ? (g_cdst[r0 + cb + t] - n0) : -1;
    // --- MFMA phase: wave w computes rows [cb + w*16, +16) ---
    int rloc = cb + w * 16 + (lane & 15);
    int grc = r0 + ((rloc < nrows) ? rloc : 0);
    int sn = g_csrc[grc], dn = g_cdst[grc];
    floatx4 acc[4];
#pragma unroll
    for (int nb = 0; nb < 4; ++nb)
#pragma unroll
      for (int r = 0; r < 4; ++r) acc[nb][r] = 0.f;
#pragma unroll
    for (int kk = 0; kk < 4; ++kk) {
      int node = (kk < 2) ? sn : dn;
      short8 a = *(const short8*)(hb + node * DD + (kk & 1) * 32 + chunk);
#pragma unroll
      for (int nb = 0; nb < 4; ++nb)
        acc[nb] = __builtin_amdgcn_mfma_f32_16x16x32_bf16(a, bf[kk * 4 + nb], acc[nb], 0, 0, 0);
    }
#pragma unroll
    for (int nb = 0; nb < 4; ++nb) {
#pragma unroll
      for (int r = 0; r < 4; ++r) {
        int row_l = w * 16 + 4 * (lane >> 4) + r;
        sm_msg[row_l * 66 + nb * 16 + (lane & 15)] = f2bf(lrelu(acc[nb][r] + mb[nb]));
      }
    }
    __syncthreads();
    // --- segmented aggregation: thread (c,g) walks rows g, g+4, ... ---
    {
      int cur = -1;
      float s = 0.f, q = 0.f, mx = 0.f, mn = 0.f;
      for (int r_l = g; r_l < m; r_l += 4) {
        int nd = sm_rownode[r_l];
        float v = bf2f(sm_msg[r_l * 66 + c]);
        if (nd != cur) {
          if (cur >= 0) {
            atomicAdd(&sm_s[cur * 64 + c], s);
            atomicAdd(&sm_q[cur * 64 + c], q);
            atomicMax(&sm_mx[cur * 64 + c], omap(mx));
            atomicMin(&sm_mn[cur * 64 + c], omap(mn));
          }
          cur = nd; s = 0.f; q = 0.f; mx = -3.4e38f; mn = 3.4e38f;
        }
        s += v; q += v * v; mx = fmaxf(mx, v); mn = fminf(mn, v);
      }
      if (cur >= 0) {
        atomicAdd(&sm_s[cur * 64 + c], s);
        atomicAdd(&sm_q[cur * 64 + c], q);
        atomicMax(&sm_mx[cur * 64 + c], omap(mx));
        atomicMin(&sm_mn[cur * 64 + c], omap(mn));
      }
    }
    __syncthreads();  // protect sm_msg/rownode reuse
  }

  // --- finalize: stats -> scalers -> g_x rows ---
  int cntn = n1 - n0;
  for (int nl = g; nl < cntn; nl += 4) {
    int node = n0 + nl;
    int deg = g_roff[node + 1] - g_roff[node];
    float degc = fmaxf((float)deg, 1.f);
    float s = sm_s[nl * 64 + c], q = sm_q[nl * 64 + c];
    float mean = s / degc;
    float var = fmaxf(q / degc - mean * mean, 0.f);
    float sd = sqrtf(var + 1e-30f);
    float mx = oinv(sm_mx[nl * 64 + c]);
    float mn = oinv(sm_mn[nl * 64 + c]);
    if (deg == 0) { mean = 0.f; mx = 0.f; mn = 0.f; sd = 0.f; }
    float logd = logf(fmaxf((float)deg, 1.f) + 1.f);
    float s1 = logd / DELTA_F, s2 = DELTA_F / logd;
    unsigned short* xp = g_x + (size_t)node * UIN;
    xp[c] = hb[node * DD + c];
    xp[64 + c] = f2bf(mean);
    xp[128 + c] = f2bf(mx);
    xp[192 + c] = f2bf(mn);
    xp[256 + c] = f2bf(sd);
    xp[320 + c] = f2bf(mean * s1);
    xp[384 + c] = f2bf(mx * s1);
    xp[448 + c] = f2bf(mn * s1);
    xp[512 + c] = f2bf(sd * s1);
    xp[576 + c] = f2bf(mean * s2);
    xp[640 + c] = f2bf(mx * s2);
    xp[704 + c] = f2bf(mn * s2);
    xp[768 + c] = f2bf(sd * s2);
  }
}

// ---- fused U+mix GEMM: h_next = relu(leaky(x @ W_comb^T + b_comb) + h); final layer pools ----
__global__ void __launch_bounds__(256) k_update(int L, int par, float* __restrict__ out) {
  int lane = threadIdx.x & 63;
  int wt = blockIdx.x * 4 + (threadIdx.x >> 6);  // 32-row tiles: 1563 of them
  if (wt >= 1563) return;
  int rbase = wt * 32;
  int chunk = (lane >> 4) << 3;
  floatx4 acc[2][4];
#pragma unroll
  for (int rf = 0; rf < 2; ++rf)
#pragma unroll
    for (int nb = 0; nb < 4; ++nb)
#pragma unroll
      for (int r = 0; r < 4; ++r) acc[rf][nb][r] = 0.f;
  const unsigned short* bp = g_BfragU + (size_t)L * 26 * 4 * 512;
  for (int kk = 0; kk < 26; ++kk) {
    short8 b[4];
#pragma unroll
    for (int nb = 0; nb < 4; ++nb)
      b[nb] = *(const short8*)(bp + ((kk * 4 + nb) << 9) + lane * 8);
    short8 a[2];
#pragma unroll
    for (int rf = 0; rf < 2; ++rf) {
      int row = rbase + rf * 16 + (lane & 15);
      row = min(row, NN - 1);
      a[rf] = *(const short8*)(g_x + (size_t)row * UIN + kk * 32 + chunk);
    }
#pragma unroll
    for (int rf = 0; rf < 2; ++rf)
#pragma unroll
      for (int nb = 0; nb < 4; ++nb)
        acc[rf][nb] = __builtin_amdgcn_mfma_f32_16x16x32_bf16(a[rf], b[nb], acc[rf][nb], 0, 0, 0);
  }
  float bc[4];
#pragma unroll
  for (int nb = 0; nb < 4; ++nb) bc[nb] = g_bcomb[L * DD + nb * 16 + (lane & 15)];
  float csum[4] = {0.f, 0.f, 0.f, 0.f};
#pragma unroll
  for (int rf = 0; rf < 2; ++rf) {
#pragma unroll
    for (int nb = 0; nb < 4; ++nb) {
#pragma unroll
      for (int r = 0; r < 4; ++r) {
        int row = rbase + rf * 16 + 4 * (lane >> 4) + r;
        if (row < NN) {
          int col = nb * 16 + (lane & 15);
          float y = lrelu(acc[rf][nb][r] + bc[nb]);
          float hn = fmaxf(y + g_hf[par][row * DD + col], 0.f);
          g_hf[par ^ 1][row * DD + col] = hn;
          g_hb[par ^ 1][row * DD + col] = f2bf(hn);
          if (L == 2) csum[nb] += hn;
        }
      }
    }
  }
  if (L == 2) {
#pragma unroll
    for (int nb = 0; nb < 4; ++nb) {
      csum[nb] += __shfl_xor(csum[nb], 16);
      csum[nb] += __shfl_xor(csum[nb], 32);
    }
    if ((lane >> 4) == 0) {
#pragma unroll
      for (int nb = 0; nb < 4; ++nb) atomicAdd(out + nb * 16 + lane, csum[nb]);
    }
  }
}

extern "C" void kernel_launch(void* const* d_in, const int* in_sizes, int n_in,
                              void* d_out, int out_size, void* d_ws, size_t ws_size,
                              hipStream_t stream) {
  const float* h    = (const float*)d_in[0];
  const int*   src  = (const int*)d_in[1];
  const int*   dst  = (const int*)d_in[2];
  const float* Mw   = (const float*)d_in[3];
  const float* Mb   = (const float*)d_in[4];
  const float* Uw   = (const float*)d_in[5];
  const float* Ub   = (const float*)d_in[6];
  const float* mixw = (const float*)d_in[7];
  const float* mixb = (const float*)d_in[8];
  float* out = (float*)d_out;

  hipMemsetAsync(out, 0, (size_t)out_size * sizeof(float), stream);

  k_prep<<<12500, 256, 0, stream>>>(h);
  // CSR build + block partition (dst constant across layers -> once per call)
  k_zero<<<196, 256, 0, stream>>>();
  k_hist<<<3125, 256, 0, stream>>>(dst);
  k_scan_a<<<SCAN_BLKS, 256, 0, stream>>>();
  k_scan_b<<<1, 256, 0, stream>>>();
  k_scan_c<<<SCAN_BLKS, 256, 0, stream>>>();
  k_part<<<62, 256, 0, stream>>>();
  k_zero<<<196, 256, 0, stream>>>();
  k_scatter<<<3125, 256, 0, stream>>>(src, dst);
  // weight prep
  k_wcomb<<<624, 256, 0, stream>>>(Uw, mixw);
  k_mfrag<<<96, 256, 0, stream>>>(Mw);
  k_bcomb<<<1, 192, 0, stream>>>(mixw, Ub, mixb);

  for (int L = 0; L < NL; ++L) {
    int par = L & 1;
    k_msgagg<<<NBLK, 256, 0, stream>>>(Mb, L, par);
    k_update<<<391, 256, 0, stream>>>(L, par, out);
  }
}

// Round 4
// 506.528 us; speedup vs baseline: 1.6301x; 1.6301x over previous
//
#include <hip/hip_runtime.h>

#define NN 50000
#define EE 800000
#define DD 64
#define NL 3
#define UIN 832
#define XW 320   // stored x row: [h | mean | mx | mn | sd]
#define DELTA_F 2.833213344056216f
#define SLOPE 0.01f
#define SCAN_BLKS 196  // 196*256 = 50176 >= NN

typedef __attribute__((ext_vector_type(8))) short short8;
typedef __attribute__((ext_vector_type(4))) float floatx4;

// ---- static device buffers (fully rewritten every call) ----
__device__ __align__(16) float          g_hf[2][NN * DD];       // fp32 master h
__device__ __align__(16) unsigned short g_hb[2][NN * DD];       // bf16 copy for gathers
__device__ __align__(16) unsigned short g_msg[EE * DD];         // messages, CSR row order
__device__ __align__(16) unsigned short g_x2[NN * XW];          // [h | agg] bf16
__device__ __align__(16) float          g_sc[NN * 2];           // per-node (s1, s2)
__device__ __align__(16) unsigned short g_BfragU[NL * 26 * 4 * 512]; // W_comb^T fragments
__device__ __align__(16) unsigned short g_BfragM[NL * 4 * 4 * 512];  // M_w^T fragments
__device__ float g_bcomb[NL * DD];
__device__ int   g_cnt[NN];
__device__ int   g_roff[NN + 1];
__device__ int   g_csrc[EE];      // src node per CSR row (coalesced for k_edge)
__device__ int   g_cdst[EE];      // dst node per CSR row
__device__ int   g_bsum[SCAN_BLKS], g_boff[SCAN_BLKS];

__device__ __forceinline__ float bf2f(unsigned short u) {
  return __uint_as_float(((unsigned)u) << 16);
}
__device__ __forceinline__ unsigned short f2bf(float f) {
  unsigned u = __float_as_uint(f);
  return (unsigned short)((u + 0x7FFFu + ((u >> 16) & 1u)) >> 16);
}
__device__ __forceinline__ float lrelu(float x) { return x >= 0.f ? x : SLOPE * x; }

// ---- prep: h = round(h*100)/100, plus bf16 copy ----
__global__ void __launch_bounds__(256) k_prep(const float* __restrict__ h) {
  int i = blockIdx.x * 256 + threadIdx.x;
  if (i >= NN * DD) return;
  float v = rintf(h[i] * 100.f) / 100.f;
  g_hf[0][i] = v;
  g_hb[0][i] = f2bf(v);
}

__global__ void __launch_bounds__(256) k_zero() {
  int i = blockIdx.x * 256 + threadIdx.x;
  if (i < NN) g_cnt[i] = 0;
}

__global__ void __launch_bounds__(256) k_hist(const int* __restrict__ dst) {
  int i = blockIdx.x * 256 + threadIdx.x;
  if (i < EE) atomicAdd(&g_cnt[dst[i]], 1);
}

// ---- hierarchical scan: (a) per-block reduce, (b) scan partials, (c) in-block scan ----
__global__ void __launch_bounds__(256) k_scan_a() {
  __shared__ int sh[256];
  int t = threadIdx.x;
  int idx = blockIdx.x * 256 + t;
  sh[t] = (idx < NN) ? g_cnt[idx] : 0;
  __syncthreads();
  for (int off = 128; off > 0; off >>= 1) {
    if (t < off) sh[t] += sh[t + off];
    __syncthreads();
  }
  if (t == 0) g_bsum[blockIdx.x] = sh[0];
}

__global__ void __launch_bounds__(256) k_scan_b() {
  __shared__ int sh[256];
  int t = threadIdx.x;
  sh[t] = (t < SCAN_BLKS) ? g_bsum[t] : 0;
  __syncthreads();
  for (int off = 1; off < 256; off <<= 1) {
    int v = (t >= off) ? sh[t - off] : 0;
    __syncthreads();
    sh[t] += v;
    __syncthreads();
  }
  if (t < SCAN_BLKS) g_boff[t] = (t == 0) ? 0 : sh[t - 1];
}

__global__ void __launch_bounds__(256) k_scan_c() {
  __shared__ int sh[256];
  int t = threadIdx.x;
  int idx = blockIdx.x * 256 + t;
  int v = (idx < NN) ? g_cnt[idx] : 0;
  sh[t] = v;
  __syncthreads();
  for (int off = 1; off < 256; off <<= 1) {
    int x = (t >= off) ? sh[t - off] : 0;
    __syncthreads();
    sh[t] += x;
    __syncthreads();
  }
  if (idx < NN) g_roff[idx] = g_boff[blockIdx.x] + sh[t] - v;  // exclusive prefix
  if (blockIdx.x == 0 && t == 0) g_roff[NN] = EE;              // total is known
}

__global__ void __launch_bounds__(256) k_scatter(const int* __restrict__ src,
                                                 const int* __restrict__ dst) {
  int i = blockIdx.x * 256 + threadIdx.x;
  if (i < EE) {
    int d = dst[i];
    int p = atomicAdd(&g_cnt[d], 1);
    int pos = g_roff[d] + p;
    g_csrc[pos] = src[i];
    g_cdst[pos] = d;
  }
}

// ---- W_comb = mix_w @ U_w, written directly into MFMA B-fragment layout ----
__global__ void __launch_bounds__(256) k_wcomb(const float* __restrict__ Uw,
                                               const float* __restrict__ mixw) {
  int idx = blockIdx.x * 256 + threadIdx.x;  // NL*DD*UIN = 159744
  if (idx >= NL * DD * UIN) return;
  int l = idx / (DD * UIN);
  int rem = idx - l * (DD * UIN);
  int d = rem / UIN;
  int k = rem - d * UIN;
  const float* xw = mixw + (l * DD + d) * DD;
  const float* uc = Uw + (size_t)l * DD * UIN + k;
  float s = 0.f;
  for (int j = 0; j < DD; ++j) s += xw[j] * uc[(size_t)j * UIN];
  int kt = k >> 5, kr = k & 31, g = kr >> 3, j8 = kr & 7, nb = d >> 4;
  int ln = (g << 4) | (d & 15);
  g_BfragU[(((l * 26 + kt) * 4 + nb) << 9) + ln * 8 + j8] = f2bf(s);
}

__global__ void __launch_bounds__(256) k_mfrag(const float* __restrict__ Mw) {
  int idx = blockIdx.x * 256 + threadIdx.x;  // NL*DD*128 = 24576
  if (idx >= NL * DD * 128) return;
  int l = idx >> 13;
  int rem = idx & 8191;
  int d = rem >> 7;
  int k = rem & 127;
  float w = Mw[idx];
  int kt = k >> 5, kr = k & 31, g = kr >> 3, j8 = kr & 7, nb = d >> 4;
  int ln = (g << 4) | (d & 15);
  g_BfragM[(((l * 4 + kt) * 4 + nb) << 9) + ln * 8 + j8] = f2bf(w);
}

__global__ void __launch_bounds__(192) k_bcomb(const float* __restrict__ mixw,
                                               const float* __restrict__ Ub,
                                               const float* __restrict__ mixb) {
  int idx = threadIdx.x;  // 192
  int l = idx >> 6, d = idx & 63;
  const float* xw = mixw + (l * DD + d) * DD;
  const float* ub = Ub + l * DD;
  float s = 0.f;
  for (int j = 0; j < DD; ++j) s += xw[j] * ub[j];
  g_bcomb[idx] = s + mixb[idx];
}

// ---- edge GEMM: msg[row] = leaky(M @ [h_src || h_dst] + Mb), rows in CSR order ----
__global__ void __launch_bounds__(256) k_edge(const float* __restrict__ Mb,
                                              int L, int par) {
  int lane = threadIdx.x & 63;
  int wid = blockIdx.x * 4 + (threadIdx.x >> 6);
  int nw = gridDim.x * 4;
  short8 bf[16];
  const unsigned short* bp = g_BfragM + ((size_t)L * 16) * 512;
#pragma unroll
  for (int i = 0; i < 16; ++i)
    bf[i] = *(const short8*)(bp + i * 512 + lane * 8);
  float mb[4];
#pragma unroll
  for (int nb = 0; nb < 4; ++nb) mb[nb] = Mb[L * DD + nb * 16 + (lane & 15)];
  const unsigned short* hb = g_hb[par];
  int chunk = (lane >> 4) << 3;

  for (int wt = wid; wt < EE / 16; wt += nw) {
    int base = wt * 16 + (lane & 15);
    int sn = g_csrc[base], dn = g_cdst[base];   // coalesced CSR-ordered indices
    floatx4 acc[4];
#pragma unroll
    for (int nb = 0; nb < 4; ++nb)
#pragma unroll
      for (int r = 0; r < 4; ++r) acc[nb][r] = 0.f;
#pragma unroll
    for (int kk = 0; kk < 4; ++kk) {
      int node = (kk < 2) ? sn : dn;
      short8 a = *(const short8*)(hb + node * DD + (kk & 1) * 32 + chunk);
#pragma unroll
      for (int nb = 0; nb < 4; ++nb)
        acc[nb] = __builtin_amdgcn_mfma_f32_16x16x32_bf16(a, bf[kk * 4 + nb], acc[nb], 0, 0, 0);
    }
#pragma unroll
    for (int nb = 0; nb < 4; ++nb) {
#pragma unroll
      for (int r = 0; r < 4; ++r) {
        float v = lrelu(acc[nb][r] + mb[nb]);
        int row = wt * 16 + 4 * (lane >> 4) + r;
        g_msg[row * DD + nb * 16 + (lane & 15)] = f2bf(v);
      }
    }
  }
}

// ---- per-node aggregation -> x2 row [h | mean | mx | mn | sd] + (s1,s2) ----
__global__ void __launch_bounds__(256) k_agg(int par) {
  int lane = threadIdx.x & 63;
  int n = blockIdx.x * 4 + (threadIdx.x >> 6);
  int r0 = g_roff[n], r1 = g_roff[n + 1];
  float s = 0.f, q = 0.f, mx = -3.4e38f, mn = 3.4e38f;
  for (int r = r0; r < r1; ++r) {
    float v = bf2f(g_msg[r * DD + lane]);
    s += v;
    q += v * v;
    mx = fmaxf(mx, v);
    mn = fminf(mn, v);
  }
  float deg = (float)(r1 - r0);
  float degc = fmaxf(deg, 1.f);
  float mean = s / degc;
  float var = fmaxf(q / degc - mean * mean, 0.f);
  float sd = sqrtf(var + 1e-30f);
  if (r1 == r0) { mx = 0.f; mn = 0.f; sd = 0.f; }
  float logd = logf(fmaxf(deg, 1.f) + 1.f);
  unsigned short* xp = g_x2 + (size_t)n * XW;
  xp[lane] = g_hb[par][n * DD + lane];
  xp[64 + lane] = f2bf(mean);
  xp[128 + lane] = f2bf(mx);
  xp[192 + lane] = f2bf(mn);
  xp[256 + lane] = f2bf(sd);
  if (lane == 0) {
    g_sc[n * 2]     = logd / DELTA_F;
    g_sc[n * 2 + 1] = DELTA_F / logd;
  }
}

// ---- fused U+mix GEMM with per-node scalers applied post-GEMM ----
// out = U0*[h|agg] + s1*(U2*agg) + s2*(U3*agg) + b_comb; then leaky, +h, relu
__global__ void __launch_bounds__(256) k_update(int L, int par, float* __restrict__ out) {
  int lane = threadIdx.x & 63;
  int wt = blockIdx.x * 4 + (threadIdx.x >> 6);  // 32-row tiles: 1563 of them
  if (wt >= 1563) return;
  int rbase = wt * 32;
  int chunk = (lane >> 4) << 3;
  floatx4 acc0[2][4], acc2[2][4], acc3[2][4];
#pragma unroll
  for (int rf = 0; rf < 2; ++rf)
#pragma unroll
    for (int nb = 0; nb < 4; ++nb)
#pragma unroll
      for (int r = 0; r < 4; ++r) { acc0[rf][nb][r] = 0.f; acc2[rf][nb][r] = 0.f; acc3[rf][nb][r] = 0.f; }
  const unsigned short* bp = g_BfragU + (size_t)L * 26 * 4 * 512;
  int rowA[2];
#pragma unroll
  for (int rf = 0; rf < 2; ++rf) rowA[rf] = min(rbase + rf * 16 + (lane & 15), NN - 1);

  // group 0: kt 0..9 over x2 cols [0,320) — identity+unit-scaled agg blocks
  for (int kk = 0; kk < 10; ++kk) {
    short8 b[4];
#pragma unroll
    for (int nb = 0; nb < 4; ++nb)
      b[nb] = *(const short8*)(bp + ((kk * 4 + nb) << 9) + lane * 8);
    short8 a[2];
#pragma unroll
    for (int rf = 0; rf < 2; ++rf)
      a[rf] = *(const short8*)(g_x2 + (size_t)rowA[rf] * XW + kk * 32 + chunk);
#pragma unroll
    for (int rf = 0; rf < 2; ++rf)
#pragma unroll
      for (int nb = 0; nb < 4; ++nb)
        acc0[rf][nb] = __builtin_amdgcn_mfma_f32_16x16x32_bf16(a[rf], b[nb], acc0[rf][nb], 0, 0, 0);
  }
  // groups 2,3: kt 10..17 and 18..25 over the SAME agg cols [64,320)
  for (int kk = 0; kk < 8; ++kk) {
    short8 a[2];
#pragma unroll
    for (int rf = 0; rf < 2; ++rf)
      a[rf] = *(const short8*)(g_x2 + (size_t)rowA[rf] * XW + 64 + kk * 32 + chunk);
    short8 b2[4], b3[4];
#pragma unroll
    for (int nb = 0; nb < 4; ++nb) {
      b2[nb] = *(const short8*)(bp + (((10 + kk) * 4 + nb) << 9) + lane * 8);
      b3[nb] = *(const short8*)(bp + (((18 + kk) * 4 + nb) << 9) + lane * 8);
    }
#pragma unroll
    for (int rf = 0; rf < 2; ++rf)
#pragma unroll
      for (int nb = 0; nb < 4; ++nb) {
        acc2[rf][nb] = __builtin_amdgcn_mfma_f32_16x16x32_bf16(a[rf], b2[nb], acc2[rf][nb], 0, 0, 0);
        acc3[rf][nb] = __builtin_amdgcn_mfma_f32_16x16x32_bf16(a[rf], b3[nb], acc3[rf][nb], 0, 0, 0);
      }
  }

  float bc[4];
#pragma unroll
  for (int nb = 0; nb < 4; ++nb) bc[nb] = g_bcomb[L * DD + nb * 16 + (lane & 15)];
  float csum[4] = {0.f, 0.f, 0.f, 0.f};
#pragma unroll
  for (int rf = 0; rf < 2; ++rf) {
#pragma unroll
    for (int r = 0; r < 4; ++r) {
      int row = rbase + rf * 16 + 4 * (lane >> 4) + r;
      if (row < NN) {
        float s1 = g_sc[row * 2], s2 = g_sc[row * 2 + 1];
#pragma unroll
        for (int nb = 0; nb < 4; ++nb) {
          int col = nb * 16 + (lane & 15);
          float y = lrelu(acc0[rf][nb][r] + s1 * acc2[rf][nb][r] + s2 * acc3[rf][nb][r] + bc[nb]);
          float hn = fmaxf(y + g_hf[par][row * DD + col], 0.f);
          g_hf[par ^ 1][row * DD + col] = hn;
          g_hb[par ^ 1][row * DD + col] = f2bf(hn);
          if (L == 2) csum[nb] += hn;
        }
      }
    }
  }
  if (L == 2) {
#pragma unroll
    for (int nb = 0; nb < 4; ++nb) {
      csum[nb] += __shfl_xor(csum[nb], 16);
      csum[nb] += __shfl_xor(csum[nb], 32);
    }
    if ((lane >> 4) == 0) {
#pragma unroll
      for (int nb = 0; nb < 4; ++nb) atomicAdd(out + nb * 16 + lane, csum[nb]);
    }
  }
}

extern "C" void kernel_launch(void* const* d_in, const int* in_sizes, int n_in,
                              void* d_out, int out_size, void* d_ws, size_t ws_size,
                              hipStream_t stream) {
  const float* h    = (const float*)d_in[0];
  const int*   src  = (const int*)d_in[1];
  const int*   dst  = (const int*)d_in[2];
  const float* Mw   = (const float*)d_in[3];
  const float* Mb   = (const float*)d_in[4];
  const float* Uw   = (const float*)d_in[5];
  const float* Ub   = (const float*)d_in[6];
  const float* mixw = (const float*)d_in[7];
  const float* mixb = (const float*)d_in[8];
  float* out = (float*)d_out;

  hipMemsetAsync(out, 0, (size_t)out_size * sizeof(float), stream);

  k_prep<<<12500, 256, 0, stream>>>(h);
  // CSR build (dst constant across layers -> once per call)
  k_zero<<<196, 256, 0, stream>>>();
  k_hist<<<3125, 256, 0, stream>>>(dst);
  k_scan_a<<<SCAN_BLKS, 256, 0, stream>>>();
  k_scan_b<<<1, 256, 0, stream>>>();
  k_scan_c<<<SCAN_BLKS, 256, 0, stream>>>();
  k_zero<<<196, 256, 0, stream>>>();
  k_scatter<<<3125, 256, 0, stream>>>(src, dst);
  // weight prep
  k_wcomb<<<624, 256, 0, stream>>>(Uw, mixw);
  k_mfrag<<<96, 256, 0, stream>>>(Mw);
  k_bcomb<<<1, 192, 0, stream>>>(mixw, Ub, mixb);

  for (int L = 0; L < NL; ++L) {
    int par = L & 1;
    k_edge<<<1024, 256, 0, stream>>>(Mb, L, par);
    k_agg<<<12500, 256, 0, stream>>>(par);
    k_update<<<391, 256, 0, stream>>>(L, par, out);
  }
}